// Round 1
// baseline (2297.894 us; speedup 1.0000x reference)
//
#include <hip/hip_runtime.h>
#include <cstdint>
#include <cmath>

// ---------------------------------------------------------------------------
// MEGNet block, MI355X. bf16 MFMA (16x16x32) for edge/node/state MLPs.
// ---------------------------------------------------------------------------

typedef __bf16 bf16x8 __attribute__((ext_vector_type(8)));
typedef float f32x4 __attribute__((ext_vector_type(4)));
typedef unsigned short u16x8 __attribute__((ext_vector_type(8)));
typedef unsigned short u16x4 __attribute__((ext_vector_type(4)));

__device__ __forceinline__ unsigned short f2b(float f) {
  unsigned u = __builtin_bit_cast(unsigned, f);
  u += 0x7fffu + ((u >> 16) & 1u);          // round-to-nearest-even
  return (unsigned short)(u >> 16);
}

__device__ __forceinline__ float sp_act(float x) {   // softplus = log1p(exp(x))
  return x > 15.f ? x : log1pf(__expf(x));
}

// Wave-private MFMA MLP layer: rows [m0, m0+16) of OUT = softplus(X @ WT^T + b).
// X: LDS bf16 (as u16), row stride LDX (LDX%8==0). WT: global bf16 [NOUT][K] (transposed
// weights, row-major, contiguous k). out[t][r] -> row = m0+(lane>>4)*4+r, col = t*16+(lane&15).
template<int K, int NT, int LDX>
__device__ __forceinline__ void mfma_layer(const unsigned short* X, int m0,
                                           const unsigned short* __restrict__ WT,
                                           const float* __restrict__ bias,
                                           int lane, float (&out)[NT][4]) {
  const int l15 = lane & 15, l4h = lane >> 4;
  f32x4 acc[NT];
#pragma unroll
  for (int t = 0; t < NT; ++t) acc[t] = f32x4{0.f, 0.f, 0.f, 0.f};
  const unsigned short* xp = X + (m0 + l15) * LDX + l4h * 8;
  const unsigned short* wp = WT + l15 * K + l4h * 8;
#pragma unroll
  for (int ks = 0; ks < K / 32; ++ks) {
    bf16x8 a = __builtin_bit_cast(bf16x8, *(const u16x8*)(xp + ks * 32));
#pragma unroll
    for (int t = 0; t < NT; ++t) {
      u16x8 w = *(const u16x8*)(wp + t * 16 * K + ks * 32);
      acc[t] = __builtin_amdgcn_mfma_f32_16x16x32_bf16(
          a, __builtin_bit_cast(bf16x8, w), acc[t], 0, 0, 0);
    }
  }
#pragma unroll
  for (int t = 0; t < NT; ++t) {
    float bc = bias[t * 16 + l15];
#pragma unroll
    for (int r = 0; r < 4; ++r) out[t][r] = sp_act(acc[t][r] + bc);
  }
}

template<int NT, int LDO>
__device__ __forceinline__ void store_act(unsigned short* O, int m0, int lane,
                                          const float (&v)[NT][4]) {
  const int l15 = lane & 15, l4h = lane >> 4;
#pragma unroll
  for (int t = 0; t < NT; ++t)
#pragma unroll
    for (int r = 0; r < 4; ++r)
      O[(m0 + l4h * 4 + r) * LDO + t * 16 + l15] = f2b(v[t][r]);
}

// ---------------------------------------------------------------------------
// K0: transpose+cast weights to bf16: WT[j*K+k] = bf16(W[k*N+j])
// ---------------------------------------------------------------------------
struct WPrep { const float* src; unsigned short* dst; int K; int N; };
struct PrepAll { WPrep w[11]; };

__global__ void k_prep(PrepAll P) {
  const WPrep wp = P.w[blockIdx.x];
  const int total = wp.K * wp.N;
  for (int i = threadIdx.x; i < total; i += blockDim.x) {
    const int k = i / wp.N, j = i - k * wp.N;
    wp.dst[(size_t)j * wp.K + k] = f2b(wp.src[i]);
  }
}

// ---------------------------------------------------------------------------
// K3: s = softplus(state_feat @ bs_W + bs_b)  (G=32 rows, fp32 scalar)
// ---------------------------------------------------------------------------
__global__ void k_sfeat(const float* __restrict__ state_feat, const float* __restrict__ bs_W,
                        const float* __restrict__ bs_b, float* __restrict__ s_act,
                        unsigned short* __restrict__ s_b) {
  const int o = blockIdx.x * blockDim.x + threadIdx.x;  // 0..2047
  const int g = o >> 6, c = o & 63;
  float acc = bs_b[c];
  for (int k = 0; k < 64; ++k) acc += state_feat[g * 64 + k] * bs_W[k * 64 + c];
  const float v = sp_act(acc);
  s_act[o] = v;
  s_b[o] = f2b(v);
}

// ---------------------------------------------------------------------------
// K2: n = softplus(node_feat @ bn_W + bn_b) -> bf16 n_b[N][64]
// ---------------------------------------------------------------------------
__global__ __launch_bounds__(256, 4) void k_nfeat(
    const float* __restrict__ node_feat, const unsigned short* __restrict__ bnT,
    const float* __restrict__ bn_b, unsigned short* __restrict__ n_b, int N) {
  __shared__ unsigned short Xn[64 * 72];
  const int tid = threadIdx.x, blk = blockIdx.x;
  const int lane = tid & 63, wid = tid >> 6, m0 = wid * 16;
  const int l15 = lane & 15, l4h = lane >> 4;
  for (int i = tid; i < 1024; i += 256) {
    int r = i >> 4, c4 = (i & 15) * 4;
    int gc = blk * 64 + r; if (gc >= N) gc = N - 1;
    const float4 v = *(const float4*)(node_feat + ((size_t)gc * 64 + c4));
    u16x4 p; p.x = f2b(v.x); p.y = f2b(v.y); p.z = f2b(v.z); p.w = f2b(v.w);
    *(u16x4*)(Xn + r * 72 + c4) = p;
  }
  __syncthreads();
  float o[4][4];
  mfma_layer<64, 4, 72>(Xn, m0, bnT, bn_b, lane, o);
#pragma unroll
  for (int t = 0; t < 4; ++t)
#pragma unroll
    for (int r = 0; r < 4; ++r) {
      const int g = blk * 64 + m0 + l4h * 4 + r;
      if (g < N) n_b[(size_t)g * 64 + t * 16 + l15] = f2b(o[t][r]);
    }
}

// ---------------------------------------------------------------------------
// K4: edge kernel. Per block: 64 edges.
//  X0[64][256] = [n[src] | n[dst] | e | s[batch[src]]]  (e computed in-kernel)
//  3-layer MLP -> y; out0 = y + edge_feat; scatter y into ve_sum[dst] and
//  per-graph partials.
// ---------------------------------------------------------------------------
__global__ __launch_bounds__(256, 2) void k_edge(
    const float* __restrict__ edge_feat, const int* __restrict__ eidx,
    const int* __restrict__ batch,
    const float* __restrict__ be_b, const float* __restrict__ ce_b0,
    const float* __restrict__ ce_b1, const float* __restrict__ ce_b2,
    const unsigned short* __restrict__ n_b, const unsigned short* __restrict__ s_b,
    const unsigned short* __restrict__ beT, const unsigned short* __restrict__ ce0T,
    const unsigned short* __restrict__ ce1T, const unsigned short* __restrict__ ce2T,
    float* __restrict__ out0, float* __restrict__ ve_sum, float* __restrict__ deg,
    float* __restrict__ u_edge_part, float* __restrict__ ecnt_part, int E) {
  __shared__ unsigned short X0[64 * 264];   // [64][264] (256 used, +8 pad)
  __shared__ unsigned short H0[64 * 136];
  __shared__ unsigned short H1[64 * 136];   // also aliased as Xe [64][72]
  __shared__ float U[2048];                 // per-graph partial sums [32][64]
  __shared__ float eCnt[32];
  __shared__ int sSrc[64], sDst[64], sB[64];
  const int tid = threadIdx.x, blk = blockIdx.x;
  const int lane = tid & 63, wid = tid >> 6, m0 = wid * 16;
  const int l15 = lane & 15, l4h = lane >> 4;

  for (int i = tid; i < 2048; i += 256) U[i] = 0.f;
  if (tid < 32) eCnt[tid] = 0.f;
  __syncthreads();
  if (tid < 64) {
    int g = blk * 64 + tid;
    int s = eidx[g], d = eidx[E + g];
    sSrc[tid] = s; sDst[tid] = d;
    int b = batch[s]; sB[tid] = b;
    atomicAdd(&eCnt[b], 1.f);
    atomicAdd(&deg[d], 1.f);
  }
  __syncthreads();
  // stage Xe = bf16(edge_feat rows) into H1 region, [64][72]
  for (int i = tid; i < 1024; i += 256) {
    int r = i >> 4, c4 = (i & 15) * 4;
    const float4 v = *(const float4*)(edge_feat + ((size_t)(blk * 64 + r) * 64 + c4));
    u16x4 p; p.x = f2b(v.x); p.y = f2b(v.y); p.z = f2b(v.z); p.w = f2b(v.w);
    *(u16x4*)(H1 + r * 72 + c4) = p;
  }
  // gather n[src], n[dst], s[batch[src]] (bf16, 16B chunks)
  for (int i = tid; i < 512; i += 256) {
    int r = i >> 3, p = (i & 7) * 8;
    *(u16x8*)(X0 + r * 264 + p)       = *(const u16x8*)(n_b + (size_t)sSrc[r] * 64 + p);
    *(u16x8*)(X0 + r * 264 + 64 + p)  = *(const u16x8*)(n_b + (size_t)sDst[r] * 64 + p);
    *(u16x8*)(X0 + r * 264 + 192 + p) = *(const u16x8*)(s_b + sB[r] * 64 + p);
  }
  __syncthreads();
  {  // e = softplus(edge_feat @ be_W + be_b) -> X0 cols [128,192)
    float o[4][4];
    mfma_layer<64, 4, 72>(H1, m0, beT, be_b, lane, o);
#pragma unroll
    for (int t = 0; t < 4; ++t)
#pragma unroll
      for (int r = 0; r < 4; ++r)
        X0[(m0 + l4h * 4 + r) * 264 + 128 + t * 16 + l15] = f2b(o[t][r]);
  }
  __syncthreads();  // all waves done reading Xe (H1 alias) before L1 writes H1
  {
    float o[8][4];
    mfma_layer<256, 8, 264>(X0, m0, ce0T, ce_b0, lane, o);
    store_act<8, 136>(H0, m0, lane, o);
  }
  {
    float o[8][4];
    mfma_layer<128, 8, 136>(H0, m0, ce1T, ce_b1, lane, o);
    store_act<8, 136>(H1, m0, lane, o);
  }
  {
    float o[4][4];
    mfma_layer<128, 4, 136>(H1, m0, ce2T, ce_b2, lane, o);
#pragma unroll
    for (int t = 0; t < 4; ++t)
#pragma unroll
      for (int r = 0; r < 4; ++r) {
        const int row = m0 + l4h * 4 + r;
        const int col = t * 16 + l15;
        const float y = o[t][r];
        const size_t gi = (size_t)(blk * 64 + row) * 64 + col;
        out0[gi] = y + edge_feat[gi];                       // skip connection
        atomicAdd(&ve_sum[(size_t)sDst[row] * 64 + col], y);
        atomicAdd(&U[sB[row] * 64 + col], y);
      }
  }
  __syncthreads();
  const int slot = blk & 127;
  for (int i = tid; i < 2048; i += 256) atomicAdd(&u_edge_part[slot * 2048 + i], U[i]);
  if (tid < 32) atomicAdd(&ecnt_part[slot * 32 + tid], eCnt[tid]);
}

// ---------------------------------------------------------------------------
// K5: node kernel. X[64][192] = [n | ve | s[batch]]; out1 = y + node_feat;
// scatter y into per-graph vertex partials.
// ---------------------------------------------------------------------------
__global__ __launch_bounds__(256, 2) void k_node(
    const float* __restrict__ node_feat, const int* __restrict__ batch,
    const float* __restrict__ cn_b0, const float* __restrict__ cn_b1,
    const float* __restrict__ cn_b2,
    const unsigned short* __restrict__ n_b, const unsigned short* __restrict__ s_b,
    const float* __restrict__ ve_sum, const float* __restrict__ deg,
    const unsigned short* __restrict__ cn0T, const unsigned short* __restrict__ cn1T,
    const unsigned short* __restrict__ cn2T,
    float* __restrict__ out1, float* __restrict__ u_vertex_part,
    float* __restrict__ ncnt_part, int N) {
  __shared__ unsigned short X[64 * 200];    // [64][200] (192 used)
  __shared__ unsigned short H0[64 * 136];
  __shared__ unsigned short H1[64 * 136];
  __shared__ float U[2048];
  __shared__ float nCnt[32];
  __shared__ int sB[64];
  __shared__ float sInv[64];
  const int tid = threadIdx.x, blk = blockIdx.x;
  const int lane = tid & 63, wid = tid >> 6, m0 = wid * 16;
  const int l15 = lane & 15, l4h = lane >> 4;

  for (int i = tid; i < 2048; i += 256) U[i] = 0.f;
  if (tid < 32) nCnt[tid] = 0.f;
  __syncthreads();
  if (tid < 64) {
    int g = blk * 64 + tid;
    bool valid = g < N;
    int gc = valid ? g : N - 1;
    int b = batch[gc];
    sB[tid] = b;
    sInv[tid] = 1.f / fmaxf(deg[gc], 1.f);
    if (valid) atomicAdd(&nCnt[b], 1.f);
  }
  __syncthreads();
  for (int i = tid; i < 512; i += 256) {
    int r = i >> 3, p = (i & 7) * 8;
    int gc = blk * 64 + r; if (gc >= N) gc = N - 1;
    *(u16x8*)(X + r * 200 + p)       = *(const u16x8*)(n_b + (size_t)gc * 64 + p);
    *(u16x8*)(X + r * 200 + 128 + p) = *(const u16x8*)(s_b + sB[r] * 64 + p);
  }
  for (int i = tid; i < 1024; i += 256) {   // ve = ve_sum / max(deg,1)
    int r = i >> 4, c4 = (i & 15) * 4;
    int gc = blk * 64 + r; if (gc >= N) gc = N - 1;
    const float4 v = *(const float4*)(ve_sum + ((size_t)gc * 64 + c4));
    const float s = sInv[r];
    u16x4 pk; pk.x = f2b(v.x * s); pk.y = f2b(v.y * s); pk.z = f2b(v.z * s); pk.w = f2b(v.w * s);
    *(u16x4*)(X + r * 200 + 64 + c4) = pk;
  }
  __syncthreads();
  { float o[8][4]; mfma_layer<192, 8, 200>(X, m0, cn0T, cn_b0, lane, o); store_act<8, 136>(H0, m0, lane, o); }
  { float o[8][4]; mfma_layer<128, 8, 136>(H0, m0, cn1T, cn_b1, lane, o); store_act<8, 136>(H1, m0, lane, o); }
  {
    float o[4][4];
    mfma_layer<128, 4, 136>(H1, m0, cn2T, cn_b2, lane, o);
#pragma unroll
    for (int t = 0; t < 4; ++t)
#pragma unroll
      for (int r = 0; r < 4; ++r) {
        const int row = m0 + l4h * 4 + r;
        const int g = blk * 64 + row;
        if (g < N) {
          const int col = t * 16 + l15;
          const float y = o[t][r];
          const size_t gi = (size_t)g * 64 + col;
          out1[gi] = y + node_feat[gi];
          atomicAdd(&U[sB[row] * 64 + col], y);
        }
      }
  }
  __syncthreads();
  const int slot = blk & 127;
  for (int i = tid; i < 2048; i += 256) atomicAdd(&u_vertex_part[slot * 2048 + i], U[i]);
  if (tid < 32) atomicAdd(&ncnt_part[slot * 32 + tid], nCnt[tid]);
}

// ---------------------------------------------------------------------------
// K6: state kernel (1 block, 128 threads = 2 waves).
// Reduce 128-slot partials -> means -> Xs[32][192] -> MLP -> out2.
// ---------------------------------------------------------------------------
__global__ void k_state(
    const float* __restrict__ state_feat, const float* __restrict__ s_act,
    const float* __restrict__ u_edge_part, const float* __restrict__ ecnt_part,
    const float* __restrict__ u_vertex_part, const float* __restrict__ ncnt_part,
    const unsigned short* __restrict__ cs0T, const unsigned short* __restrict__ cs1T,
    const unsigned short* __restrict__ cs2T,
    const float* __restrict__ cs_b0, const float* __restrict__ cs_b1,
    const float* __restrict__ cs_b2, float* __restrict__ out2) {
  __shared__ unsigned short Xs[32 * 200];
  __shared__ unsigned short H0[32 * 136];
  __shared__ unsigned short H1[32 * 136];
  __shared__ float ue[2048], uv[2048];
  __shared__ float ec[32], nc[32];
  const int tid = threadIdx.x;               // 128 threads
  const int lane = tid & 63, wid = tid >> 6, m0 = wid * 16;
  const int l15 = lane & 15, l4h = lane >> 4;
  for (int i = tid; i < 2048; i += 128) {
    float a = 0.f, b = 0.f;
    for (int s = 0; s < 128; ++s) {
      a += u_edge_part[s * 2048 + i];
      b += u_vertex_part[s * 2048 + i];
    }
    ue[i] = a; uv[i] = b;
  }
  if (tid < 32) {
    float a = 0.f, b = 0.f;
    for (int s = 0; s < 128; ++s) { a += ecnt_part[s * 32 + tid]; b += ncnt_part[s * 32 + tid]; }
    ec[tid] = fmaxf(a, 1.f); nc[tid] = fmaxf(b, 1.f);
  }
  __syncthreads();
  for (int i = tid; i < 2048; i += 128) {
    int g = i >> 6, c = i & 63;
    Xs[g * 200 + c]       = f2b(s_act[i]);
    Xs[g * 200 + 64 + c]  = f2b(ue[i] / ec[g]);
    Xs[g * 200 + 128 + c] = f2b(uv[i] / nc[g]);
  }
  __syncthreads();
  { float o[8][4]; mfma_layer<192, 8, 200>(Xs, m0, cs0T, cs_b0, lane, o); store_act<8, 136>(H0, m0, lane, o); }
  { float o[8][4]; mfma_layer<128, 8, 136>(H0, m0, cs1T, cs_b1, lane, o); store_act<8, 136>(H1, m0, lane, o); }
  {
    float o[4][4];
    mfma_layer<128, 4, 136>(H1, m0, cs2T, cs_b2, lane, o);
#pragma unroll
    for (int t = 0; t < 4; ++t)
#pragma unroll
      for (int r = 0; r < 4; ++r) {
        const int row = m0 + l4h * 4 + r;
        const int col = t * 16 + l15;
        out2[row * 64 + col] = o[t][r] + state_feat[row * 64 + col];
      }
  }
}

// ---------------------------------------------------------------------------
extern "C" void kernel_launch(void* const* d_in, const int* in_sizes, int n_in,
                              void* d_out, int out_size, void* d_ws, size_t ws_size,
                              hipStream_t stream) {
  const float* edge_feat  = (const float*)d_in[0];
  const float* node_feat  = (const float*)d_in[1];
  const float* state_feat = (const float*)d_in[2];
  const int*   eidx       = (const int*)d_in[3];
  const int*   batch      = (const int*)d_in[4];
  const float* be_W = (const float*)d_in[5];   const float* be_b = (const float*)d_in[6];
  const float* bn_W = (const float*)d_in[7];   const float* bn_b = (const float*)d_in[8];
  const float* bs_W = (const float*)d_in[9];   const float* bs_b = (const float*)d_in[10];
  const float* ce_W0 = (const float*)d_in[11]; const float* ce_b0 = (const float*)d_in[12];
  const float* ce_W1 = (const float*)d_in[13]; const float* ce_b1 = (const float*)d_in[14];
  const float* ce_W2 = (const float*)d_in[15]; const float* ce_b2 = (const float*)d_in[16];
  const float* cn_W0 = (const float*)d_in[17]; const float* cn_b0 = (const float*)d_in[18];
  const float* cn_W1 = (const float*)d_in[19]; const float* cn_b1 = (const float*)d_in[20];
  const float* cn_W2 = (const float*)d_in[21]; const float* cn_b2 = (const float*)d_in[22];
  const float* cs_W0 = (const float*)d_in[23]; const float* cs_b0 = (const float*)d_in[24];
  const float* cs_W1 = (const float*)d_in[25]; const float* cs_b1 = (const float*)d_in[26];
  const float* cs_W2 = (const float*)d_in[27]; const float* cs_b2 = (const float*)d_in[28];

  const int E = in_sizes[0] / 64;   // 800000
  const int N = in_sizes[1] / 64;   // 50000

  char* wsBase = (char*)d_ws;
  size_t off = 0;
  auto carve = [&](size_t bytes) -> void* {
    void* p = wsBase + off;
    off += (bytes + 255) & ~(size_t)255;
    return p;
  };
  float* ve_sum        = (float*)carve((size_t)N * 64 * 4);
  float* deg           = (float*)carve((size_t)N * 4);
  float* u_edge_part   = (float*)carve(128 * 2048 * 4);
  float* ecnt_part     = (float*)carve(128 * 32 * 4);
  float* u_vertex_part = (float*)carve(128 * 2048 * 4);
  float* ncnt_part     = (float*)carve(128 * 32 * 4);
  const size_t zeroBytes = off;
  unsigned short* n_b  = (unsigned short*)carve((size_t)N * 64 * 2);
  unsigned short* s_b  = (unsigned short*)carve(2048 * 2);
  float* s_act         = (float*)carve(2048 * 4);
  unsigned short* beT  = (unsigned short*)carve(4096 * 2);
  unsigned short* bnT  = (unsigned short*)carve(4096 * 2);
  unsigned short* ce0T = (unsigned short*)carve(32768 * 2);
  unsigned short* ce1T = (unsigned short*)carve(16384 * 2);
  unsigned short* ce2T = (unsigned short*)carve(8192 * 2);
  unsigned short* cn0T = (unsigned short*)carve(24576 * 2);
  unsigned short* cn1T = (unsigned short*)carve(16384 * 2);
  unsigned short* cn2T = (unsigned short*)carve(8192 * 2);
  unsigned short* cs0T = (unsigned short*)carve(24576 * 2);
  unsigned short* cs1T = (unsigned short*)carve(16384 * 2);
  unsigned short* cs2T = (unsigned short*)carve(8192 * 2);

  float* out0 = (float*)d_out;
  float* out1 = out0 + (size_t)E * 64;
  float* out2 = out1 + (size_t)N * 64;

  hipMemsetAsync(d_ws, 0, zeroBytes, stream);

  PrepAll P;
  P.w[0]  = {be_W, beT, 64, 64};
  P.w[1]  = {bn_W, bnT, 64, 64};
  P.w[2]  = {ce_W0, ce0T, 256, 128};
  P.w[3]  = {ce_W1, ce1T, 128, 128};
  P.w[4]  = {ce_W2, ce2T, 128, 64};
  P.w[5]  = {cn_W0, cn0T, 192, 128};
  P.w[6]  = {cn_W1, cn1T, 128, 128};
  P.w[7]  = {cn_W2, cn2T, 128, 64};
  P.w[8]  = {cs_W0, cs0T, 192, 128};
  P.w[9]  = {cs_W1, cs1T, 128, 128};
  P.w[10] = {cs_W2, cs2T, 128, 64};
  hipLaunchKernelGGL(k_prep, dim3(11), dim3(256), 0, stream, P);
  hipLaunchKernelGGL(k_sfeat, dim3(8), dim3(256), 0, stream, state_feat, bs_W, bs_b, s_act, s_b);
  const int nBlocks = (N + 63) / 64;
  hipLaunchKernelGGL(k_nfeat, dim3(nBlocks), dim3(256), 0, stream, node_feat, bnT, bn_b, n_b, N);
  hipLaunchKernelGGL(k_edge, dim3(E / 64), dim3(256), 0, stream,
                     edge_feat, eidx, batch, be_b, ce_b0, ce_b1, ce_b2,
                     n_b, s_b, beT, ce0T, ce1T, ce2T,
                     out0, ve_sum, deg, u_edge_part, ecnt_part, E);
  hipLaunchKernelGGL(k_node, dim3(nBlocks), dim3(256), 0, stream,
                     node_feat, batch, cn_b0, cn_b1, cn_b2, n_b, s_b, ve_sum, deg,
                     cn0T, cn1T, cn2T, out1, u_vertex_part, ncnt_part, N);
  hipLaunchKernelGGL(k_state, dim3(1), dim3(128), 0, stream,
                     state_feat, s_act, u_edge_part, ecnt_part, u_vertex_part, ncnt_part,
                     cs0T, cs1T, cs2T, cs_b0, cs_b1, cs_b2, out2);
}

// Round 2
// 1607.196 us; speedup vs baseline: 1.4298x; 1.4298x over previous
//
#include <hip/hip_runtime.h>
#include <cstdint>
#include <cmath>

// ---------------------------------------------------------------------------
// MEGNet block, MI355X. bf16 MFMA (16x16x32) for edge/node/state MLPs.
// R2: fast softplus (v_exp+v_log), compiler bf16 casts, LDS aliasing for
// 3 blocks/CU, parallel partial-reduction kernel.
// ---------------------------------------------------------------------------

typedef __bf16 bf16x8 __attribute__((ext_vector_type(8)));
typedef float f32x4 __attribute__((ext_vector_type(4)));
typedef unsigned short u16x8 __attribute__((ext_vector_type(8)));
typedef unsigned short u16x4 __attribute__((ext_vector_type(4)));

__device__ __forceinline__ unsigned short f2b(float f) {
  return __builtin_bit_cast(unsigned short, (__bf16)f);
}

// softplus = log1p(exp(x)); fast: native exp/log, abs err ~1e-5 (bf16 floor)
__device__ __forceinline__ float sp_act(float x) {
  float l = __logf(1.f + __expf(x));
  return x > 15.f ? x : l;
}

// Wave-private MFMA MLP layer: rows [m0, m0+16) of OUT = softplus(X @ WT^T + b).
// X: LDS bf16 (as u16), row stride LDX (LDX%8==0). WT: global bf16 [NOUT][K].
// out[t][r] -> row = m0+(lane>>4)*4+r, col = t*16+(lane&15).
template<int K, int NT, int LDX>
__device__ __forceinline__ void mfma_layer(const unsigned short* X, int m0,
                                           const unsigned short* __restrict__ WT,
                                           const float* __restrict__ bias,
                                           int lane, float (&out)[NT][4]) {
  const int l15 = lane & 15, l4h = lane >> 4;
  f32x4 acc[NT];
#pragma unroll
  for (int t = 0; t < NT; ++t) acc[t] = f32x4{0.f, 0.f, 0.f, 0.f};
  const unsigned short* xp = X + (m0 + l15) * LDX + l4h * 8;
  const unsigned short* wp = WT + l15 * K + l4h * 8;
#pragma unroll
  for (int ks = 0; ks < K / 32; ++ks) {
    bf16x8 a = __builtin_bit_cast(bf16x8, *(const u16x8*)(xp + ks * 32));
#pragma unroll
    for (int t = 0; t < NT; ++t) {
      u16x8 w = *(const u16x8*)(wp + t * 16 * K + ks * 32);
      acc[t] = __builtin_amdgcn_mfma_f32_16x16x32_bf16(
          a, __builtin_bit_cast(bf16x8, w), acc[t], 0, 0, 0);
    }
  }
#pragma unroll
  for (int t = 0; t < NT; ++t) {
    float bc = bias[t * 16 + l15];
#pragma unroll
    for (int r = 0; r < 4; ++r) out[t][r] = sp_act(acc[t][r] + bc);
  }
}

template<int NT, int LDO>
__device__ __forceinline__ void store_act(unsigned short* O, int m0, int lane,
                                          const float (&v)[NT][4]) {
  const int l15 = lane & 15, l4h = lane >> 4;
#pragma unroll
  for (int t = 0; t < NT; ++t)
#pragma unroll
    for (int r = 0; r < 4; ++r)
      O[(m0 + l4h * 4 + r) * LDO + t * 16 + l15] = f2b(v[t][r]);
}

// ---------------------------------------------------------------------------
// K0: transpose+cast weights to bf16: WT[j*K+k] = bf16(W[k*N+j]). N is pow2.
// ---------------------------------------------------------------------------
struct WPrep { const float* src; unsigned short* dst; int K; int nsh; };
struct PrepAll { WPrep w[11]; };

__global__ void k_prep(PrepAll P) {
  const WPrep wp = P.w[blockIdx.x];
  const int N = 1 << wp.nsh;
  const int total = wp.K << wp.nsh;
  for (int i = threadIdx.x; i < total; i += blockDim.x) {
    const int k = i >> wp.nsh, j = i & (N - 1);
    wp.dst[(size_t)j * wp.K + k] = f2b(wp.src[i]);
  }
}

// ---------------------------------------------------------------------------
// K1: s = softplus(state_feat @ bs_W + bs_b)  (G=32 rows, fp32 scalar)
// ---------------------------------------------------------------------------
__global__ void k_sfeat(const float* __restrict__ state_feat, const float* __restrict__ bs_W,
                        const float* __restrict__ bs_b, float* __restrict__ s_act,
                        unsigned short* __restrict__ s_b) {
  const int o = blockIdx.x * blockDim.x + threadIdx.x;  // 0..2047
  const int g = o >> 6, c = o & 63;
  float acc = bs_b[c];
  for (int k = 0; k < 64; ++k) acc += state_feat[g * 64 + k] * bs_W[k * 64 + c];
  const float v = sp_act(acc);
  s_act[o] = v;
  s_b[o] = f2b(v);
}

// ---------------------------------------------------------------------------
// K2: n = softplus(node_feat @ bn_W + bn_b) -> bf16 n_b[N][64]
// ---------------------------------------------------------------------------
__global__ __launch_bounds__(256, 4) void k_nfeat(
    const float* __restrict__ node_feat, const unsigned short* __restrict__ bnT,
    const float* __restrict__ bn_b, unsigned short* __restrict__ n_b, int N) {
  __shared__ unsigned short Xn[64 * 72];
  const int tid = threadIdx.x, blk = blockIdx.x;
  const int lane = tid & 63, wid = tid >> 6, m0 = wid * 16;
  const int l15 = lane & 15, l4h = lane >> 4;
  for (int i = tid; i < 1024; i += 256) {
    int r = i >> 4, c4 = (i & 15) * 4;
    int gc = blk * 64 + r; if (gc >= N) gc = N - 1;
    const float4 v = *(const float4*)(node_feat + ((size_t)gc * 64 + c4));
    u16x4 p; p.x = f2b(v.x); p.y = f2b(v.y); p.z = f2b(v.z); p.w = f2b(v.w);
    *(u16x4*)(Xn + r * 72 + c4) = p;
  }
  __syncthreads();
  float o[4][4];
  mfma_layer<64, 4, 72>(Xn, m0, bnT, bn_b, lane, o);
#pragma unroll
  for (int t = 0; t < 4; ++t)
#pragma unroll
    for (int r = 0; r < 4; ++r) {
      const int g = blk * 64 + m0 + l4h * 4 + r;
      if (g < N) n_b[(size_t)g * 64 + t * 16 + l15] = f2b(o[t][r]);
    }
}

// ---------------------------------------------------------------------------
// K3: edge kernel. Per block: 64 edges.
// LDS regions (aliased):
//   A: X0 [64][264] bf16  -> later H1 [64][136]
//   B: Xe [64][72]  bf16  -> then H0 [64][136] -> then U [32][64] fp32
// ---------------------------------------------------------------------------
__global__ __launch_bounds__(256, 3) void k_edge(
    const float* __restrict__ edge_feat, const int* __restrict__ eidx,
    const int* __restrict__ batch,
    const float* __restrict__ be_b, const float* __restrict__ ce_b0,
    const float* __restrict__ ce_b1, const float* __restrict__ ce_b2,
    const unsigned short* __restrict__ n_b, const unsigned short* __restrict__ s_b,
    const unsigned short* __restrict__ beT, const unsigned short* __restrict__ ce0T,
    const unsigned short* __restrict__ ce1T, const unsigned short* __restrict__ ce2T,
    float* __restrict__ out0, float* __restrict__ ve_sum, float* __restrict__ deg,
    float* __restrict__ u_edge_part, float* __restrict__ ecnt_part, int E) {
  __shared__ unsigned short A[64 * 264];   // 33792 B
  __shared__ unsigned short B[64 * 136];   // 17408 B
  __shared__ float eCnt[32];
  __shared__ int sSrc[64], sDst[64], sB[64];
  const int tid = threadIdx.x, blk = blockIdx.x;
  const int lane = tid & 63, wid = tid >> 6, m0 = wid * 16;
  const int l15 = lane & 15, l4h = lane >> 4;

  if (tid < 32) eCnt[tid] = 0.f;
  __syncthreads();
  // phase 2: indices + stage Xe -> B [64][72]
  if (tid < 64) {
    int g = blk * 64 + tid;
    int s = eidx[g], d = eidx[E + g];
    sSrc[tid] = s; sDst[tid] = d;
    int b = batch[s]; sB[tid] = b;
    atomicAdd(&eCnt[b], 1.f);
    atomicAdd(&deg[d], 1.f);
  }
  for (int i = tid; i < 1024; i += 256) {
    int r = i >> 4, c4 = (i & 15) * 4;
    const float4 v = *(const float4*)(edge_feat + ((size_t)(blk * 64 + r) * 64 + c4));
    u16x4 p; p.x = f2b(v.x); p.y = f2b(v.y); p.z = f2b(v.z); p.w = f2b(v.w);
    *(u16x4*)(B + r * 72 + c4) = p;
  }
  __syncthreads();
  // phase 3: gathers into A cols {0..127, 192..255} + e-layer into A cols 128..191
  for (int i = tid; i < 512; i += 256) {
    int r = i >> 3, p = (i & 7) * 8;
    *(u16x8*)(A + r * 264 + p)       = *(const u16x8*)(n_b + (size_t)sSrc[r] * 64 + p);
    *(u16x8*)(A + r * 264 + 64 + p)  = *(const u16x8*)(n_b + (size_t)sDst[r] * 64 + p);
    *(u16x8*)(A + r * 264 + 192 + p) = *(const u16x8*)(s_b + sB[r] * 64 + p);
  }
  {
    float o[4][4];
    mfma_layer<64, 4, 72>(B, m0, beT, be_b, lane, o);
#pragma unroll
    for (int t = 0; t < 4; ++t)
#pragma unroll
      for (int r = 0; r < 4; ++r)
        A[(m0 + l4h * 4 + r) * 264 + 128 + t * 16 + l15] = f2b(o[t][r]);
  }
  __syncthreads();  // A fully staged; all waves done reading B (Xe)
  // L0: A -> B (H0)
  {
    float o[8][4];
    mfma_layer<256, 8, 264>(A, m0, ce0T, ce_b0, lane, o);
    store_act<8, 136>(B, m0, lane, o);
  }
  __syncthreads();  // all waves done reading A (X0) before H1 overwrites it
  // L1: B -> A (H1)
  {
    float o[8][4];
    mfma_layer<128, 8, 136>(B, m0, ce1T, ce_b1, lane, o);
    store_act<8, 136>(A, m0, lane, o);
  }
  // L2: A -> regs
  float y[4][4];
  mfma_layer<128, 4, 136>(A, m0, ce2T, ce_b2, lane, y);
  // epilogue: global outputs + node scatter
#pragma unroll
  for (int t = 0; t < 4; ++t)
#pragma unroll
    for (int r = 0; r < 4; ++r) {
      const int row = m0 + l4h * 4 + r;
      const int col = t * 16 + l15;
      const size_t gi = (size_t)(blk * 64 + row) * 64 + col;
      out0[gi] = y[t][r] + edge_feat[gi];
      atomicAdd(&ve_sum[(size_t)sDst[row] * 64 + col], y[t][r]);
    }
  __syncthreads();  // all waves done with B (L1 reads)
  float* U = (float*)B;                    // 2048 fp32 in B region
  for (int i = tid; i < 2048; i += 256) U[i] = 0.f;
  __syncthreads();
#pragma unroll
  for (int t = 0; t < 4; ++t)
#pragma unroll
    for (int r = 0; r < 4; ++r) {
      const int row = m0 + l4h * 4 + r;
      atomicAdd(&U[sB[row] * 64 + t * 16 + l15], y[t][r]);
    }
  __syncthreads();
  const int slot = blk & 127;
  for (int i = tid; i < 2048; i += 256) atomicAdd(&u_edge_part[slot * 2048 + i], U[i]);
  if (tid < 32) atomicAdd(&ecnt_part[slot * 32 + tid], eCnt[tid]);
}

// ---------------------------------------------------------------------------
// K4: node kernel. A: X [64][200] -> H1 [64][136]; B: H0 -> U.
// ---------------------------------------------------------------------------
__global__ __launch_bounds__(256, 3) void k_node(
    const float* __restrict__ node_feat, const int* __restrict__ batch,
    const float* __restrict__ cn_b0, const float* __restrict__ cn_b1,
    const float* __restrict__ cn_b2,
    const unsigned short* __restrict__ n_b, const unsigned short* __restrict__ s_b,
    const float* __restrict__ ve_sum, const float* __restrict__ deg,
    const unsigned short* __restrict__ cn0T, const unsigned short* __restrict__ cn1T,
    const unsigned short* __restrict__ cn2T,
    float* __restrict__ out1, float* __restrict__ u_vertex_part,
    float* __restrict__ ncnt_part, int N) {
  __shared__ unsigned short A[64 * 200];   // 25600 B
  __shared__ unsigned short B[64 * 136];   // 17408 B
  __shared__ float nCnt[32];
  __shared__ int sB[64];
  __shared__ float sInv[64];
  const int tid = threadIdx.x, blk = blockIdx.x;
  const int lane = tid & 63, wid = tid >> 6, m0 = wid * 16;
  const int l15 = lane & 15, l4h = lane >> 4;

  if (tid < 32) nCnt[tid] = 0.f;
  __syncthreads();
  if (tid < 64) {
    int g = blk * 64 + tid;
    bool valid = g < N;
    int gc = valid ? g : N - 1;
    int b = batch[gc];
    sB[tid] = b;
    sInv[tid] = 1.f / fmaxf(deg[gc], 1.f);
    if (valid) atomicAdd(&nCnt[b], 1.f);
  }
  __syncthreads();
  for (int i = tid; i < 512; i += 256) {
    int r = i >> 3, p = (i & 7) * 8;
    int gc = blk * 64 + r; if (gc >= N) gc = N - 1;
    *(u16x8*)(A + r * 200 + p)       = *(const u16x8*)(n_b + (size_t)gc * 64 + p);
    *(u16x8*)(A + r * 200 + 128 + p) = *(const u16x8*)(s_b + sB[r] * 64 + p);
  }
  for (int i = tid; i < 1024; i += 256) {   // ve = ve_sum / max(deg,1)
    int r = i >> 4, c4 = (i & 15) * 4;
    int gc = blk * 64 + r; if (gc >= N) gc = N - 1;
    const float4 v = *(const float4*)(ve_sum + ((size_t)gc * 64 + c4));
    const float s = sInv[r];
    u16x4 pk; pk.x = f2b(v.x * s); pk.y = f2b(v.y * s); pk.z = f2b(v.z * s); pk.w = f2b(v.w * s);
    *(u16x4*)(A + r * 200 + 64 + c4) = pk;
  }
  __syncthreads();
  {
    float o[8][4];
    mfma_layer<192, 8, 200>(A, m0, cn0T, cn_b0, lane, o);
    store_act<8, 136>(B, m0, lane, o);
  }
  __syncthreads();  // all waves done reading A (X) before H1 overwrites
  {
    float o[8][4];
    mfma_layer<128, 8, 136>(B, m0, cn1T, cn_b1, lane, o);
    store_act<8, 136>(A, m0, lane, o);
  }
  float y[4][4];
  mfma_layer<128, 4, 136>(A, m0, cn2T, cn_b2, lane, y);
#pragma unroll
  for (int t = 0; t < 4; ++t)
#pragma unroll
    for (int r = 0; r < 4; ++r) {
      const int row = m0 + l4h * 4 + r;
      const int g = blk * 64 + row;
      if (g < N) {
        const size_t gi = (size_t)g * 64 + t * 16 + l15;
        out1[gi] = y[t][r] + node_feat[gi];
      }
    }
  __syncthreads();  // all waves done with B (L1 reads)
  float* U = (float*)B;
  for (int i = tid; i < 2048; i += 256) U[i] = 0.f;
  __syncthreads();
#pragma unroll
  for (int t = 0; t < 4; ++t)
#pragma unroll
    for (int r = 0; r < 4; ++r) {
      const int row = m0 + l4h * 4 + r;
      if (blk * 64 + row < N)
        atomicAdd(&U[sB[row] * 64 + t * 16 + l15], y[t][r]);
    }
  __syncthreads();
  const int slot = blk & 127;
  for (int i = tid; i < 2048; i += 256) atomicAdd(&u_vertex_part[slot * 2048 + i], U[i]);
  if (tid < 32) atomicAdd(&ncnt_part[slot * 32 + tid], nCnt[tid]);
}

// ---------------------------------------------------------------------------
// K5: parallel reduction of 128-slot partials (16 blocks x 256 threads)
// ---------------------------------------------------------------------------
__global__ void k_reduce(const float* __restrict__ u_edge_part,
                         const float* __restrict__ ecnt_part,
                         const float* __restrict__ u_vertex_part,
                         const float* __restrict__ ncnt_part,
                         float* __restrict__ ue_g, float* __restrict__ uv_g,
                         float* __restrict__ ec_g, float* __restrict__ nc_g) {
  const int i = blockIdx.x * blockDim.x + threadIdx.x;  // 0..4095
  if (i < 2048) {
    float a = 0.f;
    for (int s = 0; s < 128; ++s) a += u_edge_part[s * 2048 + i];
    ue_g[i] = a;
    if (i < 32) {
      float c = 0.f;
      for (int s = 0; s < 128; ++s) c += ecnt_part[s * 32 + i];
      ec_g[i] = fmaxf(c, 1.f);
    }
  } else {
    const int j = i - 2048;
    float a = 0.f;
    for (int s = 0; s < 128; ++s) a += u_vertex_part[s * 2048 + j];
    uv_g[j] = a;
    if (j < 32) {
      float c = 0.f;
      for (int s = 0; s < 128; ++s) c += ncnt_part[s * 32 + j];
      nc_g[j] = fmaxf(c, 1.f);
    }
  }
}

// ---------------------------------------------------------------------------
// K6: state MLP (1 block, 128 threads = 2 waves)
// ---------------------------------------------------------------------------
__global__ void k_state(
    const float* __restrict__ state_feat, const float* __restrict__ s_act,
    const float* __restrict__ ue_g, const float* __restrict__ ec_g,
    const float* __restrict__ uv_g, const float* __restrict__ nc_g,
    const unsigned short* __restrict__ cs0T, const unsigned short* __restrict__ cs1T,
    const unsigned short* __restrict__ cs2T,
    const float* __restrict__ cs_b0, const float* __restrict__ cs_b1,
    const float* __restrict__ cs_b2, float* __restrict__ out2) {
  __shared__ unsigned short Xs[32 * 200];
  __shared__ unsigned short H0[32 * 136];
  __shared__ unsigned short H1[32 * 136];
  const int tid = threadIdx.x;               // 128 threads
  const int lane = tid & 63, wid = tid >> 6, m0 = wid * 16;
  const int l15 = lane & 15, l4h = lane >> 4;
  for (int i = tid; i < 2048; i += 128) {
    int g = i >> 6, c = i & 63;
    Xs[g * 200 + c]       = f2b(s_act[i]);
    Xs[g * 200 + 64 + c]  = f2b(ue_g[i] / ec_g[g]);
    Xs[g * 200 + 128 + c] = f2b(uv_g[i] / nc_g[g]);
  }
  __syncthreads();
  { float o[8][4]; mfma_layer<192, 8, 200>(Xs, m0, cs0T, cs_b0, lane, o); store_act<8, 136>(H0, m0, lane, o); }
  { float o[8][4]; mfma_layer<128, 8, 136>(H0, m0, cs1T, cs_b1, lane, o); store_act<8, 136>(H1, m0, lane, o); }
  {
    float o[4][4];
    mfma_layer<128, 4, 136>(H1, m0, cs2T, cs_b2, lane, o);
#pragma unroll
    for (int t = 0; t < 4; ++t)
#pragma unroll
      for (int r = 0; r < 4; ++r) {
        const int row = m0 + l4h * 4 + r;
        const int col = t * 16 + l15;
        out2[row * 64 + col] = o[t][r] + state_feat[row * 64 + col];
      }
  }
}

// ---------------------------------------------------------------------------
extern "C" void kernel_launch(void* const* d_in, const int* in_sizes, int n_in,
                              void* d_out, int out_size, void* d_ws, size_t ws_size,
                              hipStream_t stream) {
  const float* edge_feat  = (const float*)d_in[0];
  const float* node_feat  = (const float*)d_in[1];
  const float* state_feat = (const float*)d_in[2];
  const int*   eidx       = (const int*)d_in[3];
  const int*   batch      = (const int*)d_in[4];
  const float* be_W = (const float*)d_in[5];   const float* be_b = (const float*)d_in[6];
  const float* bn_W = (const float*)d_in[7];   const float* bn_b = (const float*)d_in[8];
  const float* bs_W = (const float*)d_in[9];   const float* bs_b = (const float*)d_in[10];
  const float* ce_W0 = (const float*)d_in[11]; const float* ce_b0 = (const float*)d_in[12];
  const float* ce_W1 = (const float*)d_in[13]; const float* ce_b1 = (const float*)d_in[14];
  const float* ce_W2 = (const float*)d_in[15]; const float* ce_b2 = (const float*)d_in[16];
  const float* cn_W0 = (const float*)d_in[17]; const float* cn_b0 = (const float*)d_in[18];
  const float* cn_W1 = (const float*)d_in[19]; const float* cn_b1 = (const float*)d_in[20];
  const float* cn_W2 = (const float*)d_in[21]; const float* cn_b2 = (const float*)d_in[22];
  const float* cs_W0 = (const float*)d_in[23]; const float* cs_b0 = (const float*)d_in[24];
  const float* cs_W1 = (const float*)d_in[25]; const float* cs_b1 = (const float*)d_in[26];
  const float* cs_W2 = (const float*)d_in[27]; const float* cs_b2 = (const float*)d_in[28];

  const int E = in_sizes[0] / 64;   // 800000
  const int N = in_sizes[1] / 64;   // 50000

  char* wsBase = (char*)d_ws;
  size_t off = 0;
  auto carve = [&](size_t bytes) -> void* {
    void* p = wsBase + off;
    off += (bytes + 255) & ~(size_t)255;
    return p;
  };
  float* ve_sum        = (float*)carve((size_t)N * 64 * 4);
  float* deg           = (float*)carve((size_t)N * 4);
  float* u_edge_part   = (float*)carve(128 * 2048 * 4);
  float* ecnt_part     = (float*)carve(128 * 32 * 4);
  float* u_vertex_part = (float*)carve(128 * 2048 * 4);
  float* ncnt_part     = (float*)carve(128 * 32 * 4);
  const size_t zeroBytes = off;
  unsigned short* n_b  = (unsigned short*)carve((size_t)N * 64 * 2);
  unsigned short* s_b  = (unsigned short*)carve(2048 * 2);
  float* s_act         = (float*)carve(2048 * 4);
  float* ue_g          = (float*)carve(2048 * 4);
  float* uv_g          = (float*)carve(2048 * 4);
  float* ec_g          = (float*)carve(32 * 4);
  float* nc_g          = (float*)carve(32 * 4);
  unsigned short* beT  = (unsigned short*)carve(4096 * 2);
  unsigned short* bnT  = (unsigned short*)carve(4096 * 2);
  unsigned short* ce0T = (unsigned short*)carve(32768 * 2);
  unsigned short* ce1T = (unsigned short*)carve(16384 * 2);
  unsigned short* ce2T = (unsigned short*)carve(8192 * 2);
  unsigned short* cn0T = (unsigned short*)carve(24576 * 2);
  unsigned short* cn1T = (unsigned short*)carve(16384 * 2);
  unsigned short* cn2T = (unsigned short*)carve(8192 * 2);
  unsigned short* cs0T = (unsigned short*)carve(24576 * 2);
  unsigned short* cs1T = (unsigned short*)carve(16384 * 2);
  unsigned short* cs2T = (unsigned short*)carve(8192 * 2);

  float* out0 = (float*)d_out;
  float* out1 = out0 + (size_t)E * 64;
  float* out2 = out1 + (size_t)N * 64;

  hipMemsetAsync(d_ws, 0, zeroBytes, stream);

  PrepAll P;
  P.w[0]  = {be_W, beT, 64, 6};
  P.w[1]  = {bn_W, bnT, 64, 6};
  P.w[2]  = {ce_W0, ce0T, 256, 7};
  P.w[3]  = {ce_W1, ce1T, 128, 7};
  P.w[4]  = {ce_W2, ce2T, 128, 6};
  P.w[5]  = {cn_W0, cn0T, 192, 7};
  P.w[6]  = {cn_W1, cn1T, 128, 7};
  P.w[7]  = {cn_W2, cn2T, 128, 6};
  P.w[8]  = {cs_W0, cs0T, 192, 7};
  P.w[9]  = {cs_W1, cs1T, 128, 7};
  P.w[10] = {cs_W2, cs2T, 128, 6};
  hipLaunchKernelGGL(k_prep, dim3(11), dim3(256), 0, stream, P);
  hipLaunchKernelGGL(k_sfeat, dim3(8), dim3(256), 0, stream, state_feat, bs_W, bs_b, s_act, s_b);
  const int nBlocks = (N + 63) / 64;
  hipLaunchKernelGGL(k_nfeat, dim3(nBlocks), dim3(256), 0, stream, node_feat, bnT, bn_b, n_b, N);
  hipLaunchKernelGGL(k_edge, dim3(E / 64), dim3(256), 0, stream,
                     edge_feat, eidx, batch, be_b, ce_b0, ce_b1, ce_b2,
                     n_b, s_b, beT, ce0T, ce1T, ce2T,
                     out0, ve_sum, deg, u_edge_part, ecnt_part, E);
  hipLaunchKernelGGL(k_node, dim3(nBlocks), dim3(256), 0, stream,
                     node_feat, batch, cn_b0, cn_b1, cn_b2, n_b, s_b, ve_sum, deg,
                     cn0T, cn1T, cn2T, out1, u_vertex_part, ncnt_part, N);
  hipLaunchKernelGGL(k_reduce, dim3(16), dim3(256), 0, stream,
                     u_edge_part, ecnt_part, u_vertex_part, ncnt_part,
                     ue_g, uv_g, ec_g, nc_g);
  hipLaunchKernelGGL(k_state, dim3(1), dim3(128), 0, stream,
                     state_feat, s_act, ue_g, ec_g, uv_g, nc_g,
                     cs0T, cs1T, cs2T, cs_b0, cs_b1, cs_b2, out2);
}